// Round 1
// baseline (2658.130 us; speedup 1.0000x reference)
//
#include <hip/hip_runtime.h>

#define HDIM 64
#define NMODE 5
#define TOUT 6
#define TIN 5
#define NNODE 5
#define FD 10
#define SPW 12      // samples per wave (12*5 = 60 active lanes of 64)
#define ACT 60

// ---------------- ws layout (floats) ----------------
// 0      : WcE[10][192]   = embed_W @ enc_Wih^T        (folded encoder input weights)
// 1920   : bcE[192]       = embed_b @ enc_Wih^T + enc_bih
// 2112   : WcD[2][192]    = proj_W @ dec_Wih^T
// 2496   : bcD[192]       = proj_b @ dec_Wih^T + dec_bih
// 2688   : W1T[64][64]    = out_W1 transposed  (W1T[a][k] = out_W1[k][a])
// 6784   : cW1T[64][64]   = conf_W1 transposed
// 10880  : gWT[64][64]    = gat_W transposed   (gWT[r][e] = gat_W[e][r])
// 14976  : embWT[64][10]  = embed_W transposed (embWT[e][f] = embed_W[f][e])
// 15616  : end

__device__ __forceinline__ float fastrcp(float x){ return __builtin_amdgcn_rcpf(x); }
__device__ __forceinline__ float sigm(float x){ return fastrcp(1.f + __expf(-x)); }
__device__ __forceinline__ float tanh_f(float x){ return 2.f*fastrcp(1.f + __expf(-2.f*x)) - 1.f; }

__global__ void setup_kernel(const float* __restrict__ embed_W, const float* __restrict__ embed_b,
                             const float* __restrict__ enc_Wih, const float* __restrict__ enc_bih,
                             const float* __restrict__ dec_Wih, const float* __restrict__ dec_bih,
                             const float* __restrict__ proj_W,  const float* __restrict__ proj_b,
                             const float* __restrict__ out_W1,  const float* __restrict__ conf_W1,
                             const float* __restrict__ gat_W,
                             float* __restrict__ ws)
{
  const int t = threadIdx.x;
  for (int idx = t; idx < 1920; idx += 256){           // WcE[f][row]
    int f = idx / 192, row = idx % 192;
    float s = 0.f;
    for (int e = 0; e < HDIM; e++) s += embed_W[f*HDIM+e]*enc_Wih[row*HDIM+e];
    ws[idx] = s;
  }
  for (int row = t; row < 192; row += 256){            // bcE
    float s = enc_bih[row];
    for (int e = 0; e < HDIM; e++) s += embed_b[e]*enc_Wih[row*HDIM+e];
    ws[1920+row] = s;
  }
  for (int idx = t; idx < 384; idx += 256){            // WcD[c][row]
    int c = idx / 192, row = idx % 192;
    float s = 0.f;
    for (int e = 0; e < HDIM; e++) s += proj_W[c*HDIM+e]*dec_Wih[row*HDIM+e];
    ws[2112+idx] = s;
  }
  for (int row = t; row < 192; row += 256){            // bcD
    float s = dec_bih[row];
    for (int e = 0; e < HDIM; e++) s += proj_b[e]*dec_Wih[row*HDIM+e];
    ws[2496+row] = s;
  }
  for (int idx = t; idx < 4096; idx += 256){           // transposes
    int a = idx >> 6, k = idx & 63;
    ws[2688 + idx]  = out_W1 [k*HDIM + a];
    ws[6784 + idx]  = conf_W1[k*HDIM + a];
    ws[10880 + idx] = gat_W  [k*HDIM + a];
  }
  for (int idx = t; idx < 640; idx += 256){            // embWT[e][f]
    int e = idx / FD, f = idx % FD;
    ws[14976 + idx] = embed_W[f*HDIM + e];
  }
}

// One GRU step. Invariant: on entry lds[k][lane] == h[k]; on exit same (new h).
// Weights indexed uniformly -> scalar loads; h lives in VGPRs (all k-loops unrolled).
template<int NX>
__device__ __forceinline__ void gru_step(float* __restrict__ h, const float* __restrict__ xv,
    const float* __restrict__ Wc,  const float* __restrict__ bc,
    const float* __restrict__ Whh, const float* __restrict__ bhh,
    int lane, float (*lds)[64])
{
  for (int hi = 0; hi < HDIM; hi++){
    float ar  = bc[hi]          + bhh[hi];
    float az  = bc[HDIM+hi]     + bhh[HDIM+hi];
    float ani = bc[2*HDIM+hi];
    float anh = bhh[2*HDIM+hi];
    #pragma unroll
    for (int f = 0; f < NX; f++){
      ar  += xv[f]*Wc[f*192 + hi];
      az  += xv[f]*Wc[f*192 + HDIM + hi];
      ani += xv[f]*Wc[f*192 + 2*HDIM + hi];
    }
    const float* wr = Whh + hi*HDIM;
    const float* wz = Whh + (HDIM+hi)*HDIM;
    const float* wn = Whh + (2*HDIM+hi)*HDIM;
    float dr = 0.f, dz = 0.f, dn = 0.f;
    #pragma unroll
    for (int k = 0; k < HDIM; k++){
      dr += h[k]*wr[k];
      dz += h[k]*wz[k];
      dn += h[k]*wn[k];
    }
    float r = sigm(ar + dr);
    float z = sigm(az + dz);
    float n = tanh_f(ani + r*(anh + dn));
    float hold = lds[hi][lane];            // == old h[hi], avoids dynamic reg index
    lds[hi][lane] = (1.f - z)*n + z*hold;
  }
  __syncthreads();
  #pragma unroll
  for (int k = 0; k < HDIM; k++) h[k] = lds[k][lane];
  __syncthreads();
}

__global__ __launch_bounds__(64) void model_kernel(
    const float* __restrict__ x,
    const float* __restrict__ ws,
    const float* __restrict__ enc_Whh, const float* __restrict__ enc_bhh,
    const float* __restrict__ dec_Whh, const float* __restrict__ dec_bhh,
    const float* __restrict__ embed_b,
    const float* __restrict__ gat_att_src, const float* __restrict__ gat_att_dst,
    const float* __restrict__ gat_b,
    const float* __restrict__ out_b1, const float* __restrict__ out_W2, const float* __restrict__ out_b2,
    const float* __restrict__ conf_b1, const float* __restrict__ conf_W2, const float* __restrict__ conf_b2,
    float* __restrict__ traj_out, float* __restrict__ conf_out,
    int B)
{
  __shared__ float lds[HDIM][64];   // transposed [idx][lane]: conflict-free everywhere
  const int lane = threadIdx.x;
  const int sl = lane / 5;
  const int nl = lane - sl*5;
  const int samp = blockIdx.x*SPW + sl;
  const bool active = (lane < ACT) && (samp < B);
  const int sc = (samp < B) ? samp : (B-1);
  const float* xb = x + (size_t)sc*(TIN*NNODE*FD) + nl*FD;

  const float* WcE   = ws;
  const float* bcE   = ws + 1920;
  const float* WcD   = ws + 2112;
  const float* bcD   = ws + 2496;
  const float* W1T   = ws + 2688;
  const float* cW1T  = ws + 6784;
  const float* gWT   = ws + 10880;
  const float* embWT = ws + 14976;

  float h[HDIM];
  #pragma unroll
  for (int k = 0; k < HDIM; k++){ h[k] = 0.f; lds[k][lane] = 0.f; }
  __syncthreads();

  // ---------------- GRU encoder (5 steps) ----------------
  for (int t = 0; t < TIN; t++){
    float xv[FD];
    const float* xt = xb + t*(NNODE*FD);
    #pragma unroll
    for (int f = 0; f < FD; f += 2){ float2 v = *(const float2*)(xt+f); xv[f] = v.x; xv[f+1] = v.y; }
    gru_step<FD>(h, xv, WcE, bcE, enc_Whh, enc_bhh, lane, lds);
  }

  // ---------------- GAT on last frame ----------------
  float xv[FD];
  {
    const float* xt = xb + (TIN-1)*(NNODE*FD);
    #pragma unroll
    for (int f = 0; f < FD; f += 2){ float2 v = *(const float2*)(xt+f); xv[f] = v.x; xv[f+1] = v.y; }
  }
  float msum = 0.f;
  #pragma unroll
  for (int f = 0; f < 6; f++) msum += xv[f];
  const float maskf = (msum != 0.f) ? 1.f : 0.f;

  float emb[HDIM];                         // x_emb last frame (real embed, not folded)
  #pragma unroll
  for (int e = 0; e < HDIM; e++){
    float s = embed_b[e];
    #pragma unroll
    for (int f = 0; f < FD; f++) s += xv[f]*embWT[e*FD+f];
    emb[e] = s;
  }

  float asum = 0.f, adsum = 0.f;
  for (int r = 0; r < HDIM; r++){          // xl = emb @ gat_W  -> lds; + attention dots
    float s = 0.f;
    #pragma unroll
    for (int e = 0; e < HDIM; e++) s += emb[e]*gWT[r*HDIM+e];
    lds[r][lane] = s;
    asum  += s*gat_att_src[r];
    adsum += s*gat_att_dst[r];
  }
  __syncthreads();

  const int base = ((sl <= 11) ? sl : 11)*5;   // clamp idle lanes in-bounds
  float as_i[5], mk_i[5];
  #pragma unroll
  for (int i = 0; i < 5; i++){
    as_i[i] = __shfl(asum,  base+i, 64);
    mk_i[i] = __shfl(maskf, base+i, 64);
  }
  float mx = -1e30f; float al[5];
  #pragma unroll
  for (int i = 0; i < 5; i++){
    float a = as_i[i] + adsum;
    a = (a > 0.f) ? a : 0.2f*a;                       // leaky_relu 0.2
    bool valid = (i == nl) || (mk_i[i] != 0.f && maskf != 0.f);
    al[i] = valid ? a : -1e30f;
    mx = fmaxf(mx, al[i]);
  }
  float w5[5]; float esum = 0.f;
  #pragma unroll
  for (int i = 0; i < 5; i++){
    float e = (al[i] > -1e29f) ? __expf(al[i]-mx) : 0.f;
    w5[i] = e; esum += e;
  }
  const float rs = fastrcp(esum);
  #pragma unroll
  for (int i = 0; i < 5; i++) w5[i] *= rs;

  #pragma unroll
  for (int k = 0; k < HDIM; k++){                      // h_final = h_enc + gat_out
    float agg = gat_b[k];
    #pragma unroll
    for (int i = 0; i < 5; i++) agg += w5[i]*lds[k][base+i];
    h[k] += agg;
  }
  __syncthreads();
  #pragma unroll
  for (int k = 0; k < HDIM; k++) lds[k][lane] = h[k];  // restore invariant for decoder
  __syncthreads();

  // ---------------- confidence head ----------------
  float lg[NMODE];
  #pragma unroll
  for (int m = 0; m < NMODE; m++) lg[m] = conf_b2[m];
  for (int ci = 0; ci < HDIM; ci++){
    float s = conf_b1[ci];
    #pragma unroll
    for (int k = 0; k < HDIM; k++) s += h[k]*cW1T[ci*HDIM+k];
    s = fmaxf(s, 0.f);
    #pragma unroll
    for (int m = 0; m < NMODE; m++) lg[m] += s*conf_W2[ci*NMODE+m];
  }
  float cm = lg[0];
  #pragma unroll
  for (int m = 1; m < NMODE; m++) cm = fmaxf(cm, lg[m]);
  float ce = 0.f;
  #pragma unroll
  for (int m = 0; m < NMODE; m++){ lg[m] = __expf(lg[m]-cm); ce += lg[m]; }
  const float rc = fastrcp(ce);
  if (active){
    #pragma unroll
    for (int m = 0; m < NMODE; m++)
      conf_out[((size_t)samp*NMODE + m)*NNODE + nl] = lg[m]*rc;
  }

  // ---------------- GRUCell decoder (6 steps) ----------------
  float xy[2] = { xv[0], xv[1] };                      // x[:, -1, :, 0:2]
  for (int t = 0; t < TOUT; t++){
    gru_step<2>(h, xy, WcD, bcD, dec_Whh, dec_bhh, lane, lds);

    float o[10];
    #pragma unroll
    for (int oi = 0; oi < 10; oi++) o[oi] = out_b2[oi];
    for (int ai = 0; ai < HDIM; ai++){
      float s = out_b1[ai];
      #pragma unroll
      for (int k = 0; k < HDIM; k++) s += h[k]*W1T[ai*HDIM+k];
      s = fmaxf(s, 0.f);
      #pragma unroll
      for (int oi = 0; oi < 10; oi++) o[oi] += s*out_W2[ai*10+oi];
    }
    if (active){
      #pragma unroll
      for (int c = 0; c < 2; c++)
        #pragma unroll
        for (int m = 0; m < NMODE; m++)
          traj_out[(((size_t)samp*NMODE + m)*NNODE + nl)*(TOUT*2) + t*2 + c] = o[c*NMODE+m];
    }
    xy[0] = o[0]; xy[1] = o[NMODE];                    // mode-0 xy fed back
  }
}

extern "C" void kernel_launch(void* const* d_in, const int* in_sizes, int n_in,
                              void* d_out, int out_size, void* d_ws, size_t ws_size,
                              hipStream_t stream)
{
  const float* x           = (const float*)d_in[0];
  const float* embed_W     = (const float*)d_in[1];
  const float* embed_b     = (const float*)d_in[2];
  const float* gat_W       = (const float*)d_in[3];
  const float* gat_att_src = (const float*)d_in[4];
  const float* gat_att_dst = (const float*)d_in[5];
  const float* gat_b       = (const float*)d_in[6];
  const float* enc_Wih     = (const float*)d_in[7];
  const float* enc_Whh     = (const float*)d_in[8];
  const float* enc_bih     = (const float*)d_in[9];
  const float* enc_bhh     = (const float*)d_in[10];
  const float* dec_Wih     = (const float*)d_in[11];
  const float* dec_Whh     = (const float*)d_in[12];
  const float* dec_bih     = (const float*)d_in[13];
  const float* dec_bhh     = (const float*)d_in[14];
  const float* out_W1      = (const float*)d_in[15];
  const float* out_b1      = (const float*)d_in[16];
  const float* out_W2      = (const float*)d_in[17];
  const float* out_b2      = (const float*)d_in[18];
  const float* proj_W      = (const float*)d_in[19];
  const float* proj_b      = (const float*)d_in[20];
  const float* conf_W1     = (const float*)d_in[21];
  const float* conf_b1     = (const float*)d_in[22];
  const float* conf_W2     = (const float*)d_in[23];
  const float* conf_b2     = (const float*)d_in[24];

  const int B = in_sizes[0] / (TIN*NNODE*FD);
  float* ws = (float*)d_ws;
  float* traj = (float*)d_out;
  float* conf = traj + (size_t)B*NMODE*NNODE*TOUT*2;

  setup_kernel<<<1, 256, 0, stream>>>(embed_W, embed_b, enc_Wih, enc_bih, dec_Wih, dec_bih,
                                      proj_W, proj_b, out_W1, conf_W1, gat_W, ws);

  const int blocks = (B + SPW - 1) / SPW;
  model_kernel<<<blocks, 64, 0, stream>>>(x, ws,
      enc_Whh, enc_bhh, dec_Whh, dec_bhh,
      embed_b, gat_att_src, gat_att_dst, gat_b,
      out_b1, out_W2, out_b2, conf_b1, conf_W2, conf_b2,
      traj, conf, B);
}